// Round 9
// baseline (134.588 us; speedup 1.0000x reference)
//
#include <hip/hip_runtime.h>
#include <hip/hip_bf16.h>

typedef unsigned short u16;
typedef unsigned int u32;
typedef __attribute__((ext_vector_type(8))) _Float16 f16x8;
typedef __attribute__((ext_vector_type(2))) _Float16 f16x2;
typedef __attribute__((ext_vector_type(4))) float floatx4;

__device__ __forceinline__ u16 f2h(float f){
    union{_Float16 h; u16 u;}v; v.h = (_Float16)f; return v.u;   // RTN
}
__device__ __forceinline__ u32 pkh(float a, float b){
    return (u32)f2h(a) | ((u32)f2h(b) << 16);
}

#define DD 512
#define NTOK 128

// ---------------------------------------------------------------------------
// prep_k: grid (16,8,3), 512 thr. R8-proven, byte-identical (f16 datapath).
// ---------------------------------------------------------------------------
__global__ __launch_bounds__(512) void prep_k(
    const float* __restrict__ features, const float* __restrict__ W1,
    const float* __restrict__ W2, const float* __restrict__ b1,
    u16* __restrict__ Hf1b, u16* __restrict__ Hf2, u16* __restrict__ W2T)
{
    const int z = blockIdx.z;
    const int tid = threadIdx.x;

    if (z == 2) {   // W2 transpose -> f16
        __shared__ u16 tile[32][33];
        const int tx = tid & 31, ty = tid >> 5;      // ty 0..15
        const int r0 = blockIdx.x * 32, c0 = blockIdx.y * 32;
#pragma unroll
        for (int i = 0; i < 2; ++i) {
            int r = ty + i * 16;
            tile[r][tx] = f2h(W2[(size_t)(r0 + r) * 256 + (c0 + tx)]);
        }
        __syncthreads();
#pragma unroll
        for (int i = 0; i < 2; ++i) {
            int c = ty + i * 16;
            W2T[(size_t)(c0 + c) * 512 + (r0 + tx)] = tile[tx][c];
        }
        return;
    }

    const int bM = blockIdx.x, bN = blockIdx.y;
    u16* outp = z ? Hf2 : Hf1b;
    __shared__ __align__(16) u16 At[64 * 64];
    __shared__ __align__(16) u16 Btl[64 * 64];
    const int wid = tid >> 6, lane = tid & 63, lrow = lane & 15, quad = lane >> 4;
    const int wm = wid >> 1, wn = wid & 1;

    floatx4 acc[2];
    acc[0] = (floatx4)(0.0f); acc[1] = (floatx4)(0.0f);

    const int m = tid >> 3, seg = tid & 7, sw = m & 7;      // A staging map
    const int kr = tid >> 3, csB = tid & 7;                 // B staging map

    for (int kc = 0; kc < 8; ++kc) {
        const int k0 = kc * 64;
        {   // stage A: 8 fp32 -> 8 f16, one uint4, XOR-swizzled
            const float4* src = (const float4*)(features + (size_t)(bM * 64 + m) * DD + k0 + seg * 8);
            float4 f0 = src[0], f1 = src[1];
            *(uint4*)(At + m * 64 + ((seg ^ sw) << 3)) =
                make_uint4(pkh(f0.x, f0.y), pkh(f0.z, f0.w), pkh(f1.x, f1.y), pkh(f1.z, f1.w));
        }
        {   // stage B from W1 rows (transpose-in-write, swizzled scalar b16)
            const float4* src = (const float4*)(W1 + (size_t)(z * 512 + k0 + kr) * DD + bN * 64 + csB * 8);
            float4 g0 = src[0], g1 = src[1];
            float f[8] = { g0.x, g0.y, g0.z, g0.w, g1.x, g1.y, g1.z, g1.w };
            const int chunkB = (kr >> 3), offB = kr & 7;
#pragma unroll
            for (int i = 0; i < 8; ++i) {
                int c = csB * 8 + i;                        // c & 7 == i
                Btl[c * 64 + ((chunkB ^ i) << 3) + offB] = f2h(f[i]);
            }
        }
        __syncthreads();
#pragma unroll
        for (int ks = 0; ks < 2; ++ks) {
            const int ch = ks * 4 + quad;
            int r = wm * 16 + lrow;
            f16x8 afr = *(const f16x8*)(At + r * 64 + ((ch ^ (r & 7)) << 3));
#pragma unroll
            for (int j = 0; j < 2; ++j) {
                int c = wn * 32 + j * 16 + lrow;
                f16x8 bfr = *(const f16x8*)(Btl + c * 64 + ((ch ^ (c & 7)) << 3));
                acc[j] = __builtin_amdgcn_mfma_f32_16x16x32_f16(afr, bfr, acc[j], 0, 0, 0);
            }
        }
        __syncthreads();
    }
#pragma unroll
    for (int j = 0; j < 2; ++j) {
        int col = bN * 64 + wn * 32 + j * 16 + lrow;
        float bb = z ? 0.0f : b1[col];
#pragma unroll
        for (int r = 0; r < 4; ++r) {
            int row = bM * 64 + wm * 16 + quad * 4 + r;
            outp[(size_t)row * DD + col] = f2h(acc[j][r] + bb);
        }
    }
}

// ---------------------------------------------------------------------------
// Fused main — R8 datapath byte-identical (f16 packed A-stage, DMA B-staging,
// swizzles, epilogue). ONE schedule change: Btile is double-buffered
// (2 x 32K; LDS -> ~85K, 1 block/CU — R4 proved co-resident blocks add
// nothing since they contend on the same LDS port). DMA(kc+1) is issued
// BEFORE the MFMA phase into the other buffer, so its vmcnt(0) drain at the
// post-A-stage __syncthreads is covered by MFMA(kc)+A(kc+1) (~2000+ cyc >>
// DMA ~600-900) instead of A-stage alone. First barrier is lgkmcnt-only
// (raw) so the DMA stays in flight across it (guide T4: never drain vmcnt
// mid-pipeline). Race check: B[q^1] first read only after the full drain;
// B[q] overwritten only one full barrier later. Math identical -> absmax
// identical.
// ---------------------------------------------------------------------------
__global__ __launch_bounds__(512) void fused_main(
    const u16* __restrict__ Hf1b, const u16* __restrict__ Hf2,
    const u16* __restrict__ W2T, const float* __restrict__ W1,
    const float* __restrict__ b2, const float* __restrict__ W3,
    const float* __restrict__ b3, const float* __restrict__ positions,
    float* __restrict__ out)
{
    const int b = blockIdx.x, n = blockIdx.y;     // b fastest -> XCD = b
    const int tid = threadIdx.x;
    const int base_bn = b * NTOK + n;
    const int wid = tid >> 6, lane = tid & 63, lrow = lane & 15, quad = lane >> 4;

    __shared__ __align__(16) u16 c0h[DD], c1h[DD], s1h[DD];  // f16 coefs, 3 KB
    __shared__ __align__(16) char mbuf[81920];   // Atile 16K + B0 32K + B1 32K
    u16* Atile = (u16*)mbuf;                     // [128][64] swizzled, f16
    u16* Btile = (u16*)(mbuf + 16384);           // [2][256][64] swizzled, f16
    u16* gh    = (u16*)mbuf;                     // [128][136] epilogue overlay (A+B0)
    u16* w3t   = (u16*)(mbuf + 34816);           // W3^T padded [16][264] (B0 tail)

    // ---- phase 0 ----
    {
        int k = tid;  // 512 threads == DD
        c0h[k] = f2h(W1[(size_t)1024 * DD + k]);
        c1h[k] = f2h(W1[(size_t)1025 * DD + k]);
        s1h[k] = Hf1b[(size_t)base_bn * DD + k];   // already f16, b1 folded
    }
    const int mrow = tid >> 2, seg = tid & 3, swA = mrow & 7;
    float px, py;
    {
        float pnx = positions[(size_t)base_bn * 2 + 0];
        float pny = positions[(size_t)base_bn * 2 + 1];
        px = pnx - positions[(size_t)(b * NTOK + mrow) * 2 + 0];
        py = pny - positions[(size_t)(b * NTOK + mrow) * 2 + 1];
    }
    const f16x2 pxh = {(_Float16)px, (_Float16)px};
    const f16x2 pyh = {(_Float16)py, (_Float16)py};
    const f16x2 zh  = {(_Float16)0.0f, (_Float16)0.0f};
    // B-DMA lane source pointer: q-invariant swizzle (R0-proven)
    const int csrc = lane >> 3, wsrc = lane & 7;
    const u16* bsrc_lane = W2T + csrc * DD + ((wsrc ^ csrc) << 3);
    __syncthreads();

    const int wm = wid >> 2, wn = wid & 3;       // main GEMM 2x4 wave grid
    floatx4 acc[4][4];
#pragma unroll
    for (int i = 0; i < 4; ++i)
#pragma unroll
        for (int j = 0; j < 4; ++j) acc[i][j] = (floatx4)(0.0f);

    const u16* hf2p = Hf2 + (size_t)(b * NTOK + mrow) * DD;

    auto hp2 = [&](u32 h, u32 s, u32 a, u32 c) -> u32 {
        union { u32 u; f16x2 v; } H, S, A, C, O;
        H.u = h; S.u = s; A.u = a; C.u = c;
        f16x2 r = H.v + S.v;
        r = __builtin_elementwise_fma(pxh, A.v, r);
        r = __builtin_elementwise_fma(pyh, C.v, r);
        r = __builtin_elementwise_max(r, zh);
        O.v = r; return O.u;
    };

    auto ASTAGE = [&](int kc) {   // R8 A-stage verbatim
        const int kb = kc * 64 + seg * 16;
        uint4 hv  = *(const uint4*)(hf2p + kb);
        uint4 hw  = *(const uint4*)(hf2p + kb + 8);
        uint4 sv  = *(const uint4*)(s1h + kb);
        uint4 sw2 = *(const uint4*)(s1h + kb + 8);
        uint4 av  = *(const uint4*)(c0h + kb);
        uint4 aw  = *(const uint4*)(c0h + kb + 8);
        uint4 bv  = *(const uint4*)(c1h + kb);
        uint4 bw  = *(const uint4*)(c1h + kb + 8);
        uint4 o0 = make_uint4(hp2(hv.x, sv.x, av.x, bv.x), hp2(hv.y, sv.y, av.y, bv.y),
                              hp2(hv.z, sv.z, av.z, bv.z), hp2(hv.w, sv.w, av.w, bv.w));
        uint4 o1 = make_uint4(hp2(hw.x, sw2.x, aw.x, bw.x), hp2(hw.y, sw2.y, aw.y, bw.y),
                              hp2(hw.z, sw2.z, aw.z, bw.z), hp2(hw.w, sw2.w, aw.w, bw.w));
        *(uint4*)(Atile + mrow * 64 + (((seg * 2    ) ^ swA) << 3)) = o0;
        *(uint4*)(Atile + mrow * 64 + (((seg * 2 + 1) ^ swA) << 3)) = o1;
    };
    auto BDMA = [&](int kc, int qoff) {   // 4 global_load_lds into B[qoff]
#pragma unroll
        for (int q = 0; q < 4; ++q) {
            const int slot = wid * 4 + q;        // wave-uniform
            __builtin_amdgcn_global_load_lds(
                (const __attribute__((address_space(1))) u32*)(bsrc_lane + slot * 8 * DD + kc * 64),
                (__attribute__((address_space(3))) u32*)(Btile + qoff + slot * 512), 16, 0, 0);
        }
    };

    // ---- prologue: stage kc=0 into B[0]; A(0); full drain ----
    BDMA(0, 0);
    ASTAGE(0);
    __syncthreads();

    // ---- K loop: DMA(kc+1) in flight under MFMA(kc)+A(kc+1) ----
    for (int kc = 0; kc < 8; ++kc) {
        const int qs = (kc & 1) << 14;           // current B buffer (u16 offset)
        const int qn = qs ^ 16384;               // next B buffer
        if (kc < 7) BDMA(kc + 1, qn);
        {   // MFMA phase (R8 verbatim; reads Atile + B[qs])
#pragma unroll
            for (int ks = 0; ks < 2; ++ks) {
                const int ch = ks * 4 + quad;
                f16x8 afr[4], bfr[4];
#pragma unroll
                for (int i = 0; i < 4; ++i) {
                    int r = wm * 64 + i * 16 + lrow;
                    afr[i] = *(const f16x8*)(Atile + r * 64 + ((ch ^ (r & 7)) << 3));
                }
#pragma unroll
                for (int j = 0; j < 4; ++j) {
                    int c = wn * 64 + j * 16 + lrow;
                    bfr[j] = *(const f16x8*)(Btile + qs + c * 64 + ((ch ^ (c & 7)) << 3));
                }
#pragma unroll
                for (int i = 0; i < 4; ++i)
#pragma unroll
                    for (int j = 0; j < 4; ++j)
                        acc[i][j] = __builtin_amdgcn_mfma_f32_16x16x32_f16(afr[i], bfr[j], acc[i][j], 0, 0, 0);
            }
        }
        // lgkm-only barrier: all waves done reading Atile/B[qs]; DMA stays live
        asm volatile("s_waitcnt lgkmcnt(0)" ::: "memory");
        __builtin_amdgcn_s_barrier();
        if (kc < 7) {
            ASTAGE(kc + 1);
            __syncthreads();   // vmcnt(0) drain of DMA(kc+1), covered by MFMA+A
        }
    }

    // ---- w3t fill (B0 tail region; dead for epilogue) ----
    {   // w3t: W3 (256x4 fp32) transposed, padded to 16 cols, f16
        int c = tid & 15, kb2 = tid >> 4;          // kb2 0..31
        int k0w = kb2 * 8;
        u32 wv[4];
#pragma unroll
        for (int p = 0; p < 4; ++p) {
            int ka = k0w + p * 2;
            u16 va = (c < 4) ? f2h(W3[ka * 4 + c])       : (u16)0;
            u16 vb = (c < 4) ? f2h(W3[(ka + 1) * 4 + c]) : (u16)0;
            wv[p] = (u32)va | ((u32)vb << 16);
        }
        *(uint2*)(w3t + c * 264 + k0w)     = make_uint2(wv[0], wv[1]);
        *(uint2*)(w3t + c * 264 + k0w + 4) = make_uint2(wv[2], wv[3]);
    }

    // ---- epilogue: relu(acc+b2) -> gh f16 halves -> layer-3 MFMA (R8) ----
    float b2v[4];
#pragma unroll
    for (int j = 0; j < 4; ++j) b2v[j] = b2[wn * 64 + j * 16 + lrow];

    const int smrow = wid * 16;                  // per-wave epilogue row block
    floatx4 acc3 = (floatx4)(0.0f);
#pragma unroll
    for (int half = 0; half < 2; ++half) {
        __syncthreads();
        if ((wn >> 1) == half) {
#pragma unroll
            for (int i = 0; i < 4; ++i)
#pragma unroll
                for (int j = 0; j < 4; ++j)
#pragma unroll
                    for (int r = 0; r < 4; ++r) {
                        int row = wm * 64 + i * 16 + quad * 4 + r;
                        int col = (wn & 1) * 64 + j * 16 + lrow;
                        gh[row * 136 + col] = f2h(fmaxf(acc[i][j][r] + b2v[j], 0.0f));
                    }
        }
        __syncthreads();
#pragma unroll
        for (int ks = 0; ks < 4; ++ks) {
            f16x8 gfrag = *(const f16x8*)(gh + (smrow + lrow) * 136 + ks * 32 + quad * 8);
            f16x8 wfrag = *(const f16x8*)(w3t + lrow * 264 + half * 128 + ks * 32 + quad * 8);
            acc3 = __builtin_amdgcn_mfma_f32_16x16x32_f16(gfrag, wfrag, acc3, 0, 0, 0);
        }
    }
    if (lrow < 4) {
        float bo = b3[lrow];
#pragma unroll
        for (int r = 0; r < 4; ++r) {
            int row = smrow + quad * 4 + r;
            out[(size_t)base_bn * 512 + row * 4 + lrow] = acc3[r] + bo;
        }
    }
}

// ---------------------------------------------------------------------------
extern "C" void kernel_launch(void* const* d_in, const int* in_sizes, int n_in,
                              void* d_out, int out_size, void* d_ws, size_t ws_size,
                              hipStream_t stream)
{
    const float* features  = (const float*)d_in[0];
    const float* positions = (const float*)d_in[1];
    const float* W1 = (const float*)d_in[2];
    const float* b1 = (const float*)d_in[3];
    const float* W2 = (const float*)d_in[4];
    const float* b2 = (const float*)d_in[5];
    const float* W3 = (const float*)d_in[6];
    const float* b3 = (const float*)d_in[7];
    float* out = (float*)d_out;

    char* ws = (char*)d_ws;
    u16* W2T  = (u16*)(ws);                 // 256*512*2 = 262144 B
    u16* Hf1b = (u16*)(ws + 262144);        // 1048576 B
    u16* Hf2  = (u16*)(ws + 1310720);       // 1048576 B (total 2.25 MB)

    prep_k<<<dim3(16, 8, 3), 512, 0, stream>>>(features, W1, W2, b1, Hf1b, Hf2, W2T);
    fused_main<<<dim3(8, 128), 512, 0, stream>>>(Hf1b, Hf2, W2T, W1, b2, W3, b3,
                                                 positions, out);
}

// Round 10
// 114.922 us; speedup vs baseline: 1.1711x; 1.1711x over previous
//
#include <hip/hip_runtime.h>
#include <hip/hip_bf16.h>

typedef unsigned short u16;
typedef unsigned int u32;
typedef __attribute__((ext_vector_type(8))) _Float16 f16x8;
typedef __attribute__((ext_vector_type(2))) _Float16 f16x2;
typedef __attribute__((ext_vector_type(4))) float floatx4;

__device__ __forceinline__ u16 f2h(float f){
    union{_Float16 h; u16 u;}v; v.h = (_Float16)f; return v.u;   // RTN
}
__device__ __forceinline__ u32 pkh(float a, float b){
    return (u32)f2h(a) | ((u32)f2h(b) << 16);
}

#define DD 512
#define NTOK 128

// ---------------------------------------------------------------------------
// prep_k: grid (16,8,3), 512 thr. R8 structure; epilogue now folds the
// rank-2 position term:  u[i,k] = pos[i,0]*c0[k] + pos[i,1]*c1[k]
//   z=0: Hf1b = h1 + b1 + u[n]     (n = token row)
//   z=1: Hf2  = h2 - u[m]
// so fused_main's A-stage is a pure add+relu (no position math at all).
// ---------------------------------------------------------------------------
__global__ __launch_bounds__(512) void prep_k(
    const float* __restrict__ features, const float* __restrict__ W1,
    const float* __restrict__ W2, const float* __restrict__ b1,
    const float* __restrict__ positions,
    u16* __restrict__ Hf1b, u16* __restrict__ Hf2, u16* __restrict__ W2T)
{
    const int z = blockIdx.z;
    const int tid = threadIdx.x;

    if (z == 2) {   // W2 transpose -> f16
        __shared__ u16 tile[32][33];
        const int tx = tid & 31, ty = tid >> 5;      // ty 0..15
        const int r0 = blockIdx.x * 32, c0 = blockIdx.y * 32;
#pragma unroll
        for (int i = 0; i < 2; ++i) {
            int r = ty + i * 16;
            tile[r][tx] = f2h(W2[(size_t)(r0 + r) * 256 + (c0 + tx)]);
        }
        __syncthreads();
#pragma unroll
        for (int i = 0; i < 2; ++i) {
            int c = ty + i * 16;
            W2T[(size_t)(c0 + c) * 512 + (r0 + tx)] = tile[tx][c];
        }
        return;
    }

    const int bM = blockIdx.x, bN = blockIdx.y;
    u16* outp = z ? Hf2 : Hf1b;
    __shared__ __align__(16) u16 At[64 * 64];
    __shared__ __align__(16) u16 Btl[64 * 64];
    const int wid = tid >> 6, lane = tid & 63, lrow = lane & 15, quad = lane >> 4;
    const int wm = wid >> 1, wn = wid & 1;

    floatx4 acc[2];
    acc[0] = (floatx4)(0.0f); acc[1] = (floatx4)(0.0f);

    const int m = tid >> 3, seg = tid & 7, sw = m & 7;      // A staging map
    const int kr = tid >> 3, csB = tid & 7;                 // B staging map

    for (int kc = 0; kc < 8; ++kc) {
        const int k0 = kc * 64;
        {   // stage A: 8 fp32 -> 8 f16, one uint4, XOR-swizzled
            const float4* src = (const float4*)(features + (size_t)(bM * 64 + m) * DD + k0 + seg * 8);
            float4 f0 = src[0], f1 = src[1];
            *(uint4*)(At + m * 64 + ((seg ^ sw) << 3)) =
                make_uint4(pkh(f0.x, f0.y), pkh(f0.z, f0.w), pkh(f1.x, f1.y), pkh(f1.z, f1.w));
        }
        {   // stage B from W1 rows (transpose-in-write, swizzled scalar b16)
            const float4* src = (const float4*)(W1 + (size_t)(z * 512 + k0 + kr) * DD + bN * 64 + csB * 8);
            float4 g0 = src[0], g1 = src[1];
            float f[8] = { g0.x, g0.y, g0.z, g0.w, g1.x, g1.y, g1.z, g1.w };
            const int chunkB = (kr >> 3), offB = kr & 7;
#pragma unroll
            for (int i = 0; i < 8; ++i) {
                int c = csB * 8 + i;                        // c & 7 == i
                Btl[c * 64 + ((chunkB ^ i) << 3) + offB] = f2h(f[i]);
            }
        }
        __syncthreads();
#pragma unroll
        for (int ks = 0; ks < 2; ++ks) {
            const int ch = ks * 4 + quad;
            int r = wm * 16 + lrow;
            f16x8 afr = *(const f16x8*)(At + r * 64 + ((ch ^ (r & 7)) << 3));
#pragma unroll
            for (int j = 0; j < 2; ++j) {
                int c = wn * 32 + j * 16 + lrow;
                f16x8 bfr = *(const f16x8*)(Btl + c * 64 + ((ch ^ (c & 7)) << 3));
                acc[j] = __builtin_amdgcn_mfma_f32_16x16x32_f16(afr, bfr, acc[j], 0, 0, 0);
            }
        }
        __syncthreads();
    }
#pragma unroll
    for (int j = 0; j < 2; ++j) {
        int col = bN * 64 + wn * 32 + j * 16 + lrow;
        float bb  = z ? 0.0f : b1[col];
        float c0v = W1[(size_t)1024 * DD + col];     // W1c row 0
        float c1v = W1[(size_t)1025 * DD + col];     // W1c row 1
        float sgn = z ? -1.0f : 1.0f;
#pragma unroll
        for (int r = 0; r < 4; ++r) {
            int row = bM * 64 + wm * 16 + quad * 4 + r;     // token index
            float pxr = positions[(size_t)row * 2 + 0];
            float pyr = positions[(size_t)row * 2 + 1];
            outp[(size_t)row * DD + col] =
                f2h(acc[j][r] + bb + sgn * (pxr * c0v + pyr * c1v));
        }
    }
}

// ---------------------------------------------------------------------------
// Fused main — R8 frame byte-identical (single Btile, DMA staging, 2 barriers
// per kc, swizzles, epilogue) with the position math algebraically removed:
// A-stage is now  h = relu(hf2'[m,k] + s1'[n,k])  — one packed add + max per
// 2 elems (u folded into both tables by prep_k). c0h/c1h LDS arrays, the
// positions loads and px/py all deleted: coef LDS traffic drops 3x, A-stage
// VALU halves. R9's double-buffer reverted (2 resident blocks are the proven
// drain cover; R9 showed losing one costs 16 us).
// ---------------------------------------------------------------------------
__global__ __launch_bounds__(512) void fused_main(
    const u16* __restrict__ Hf1b, const u16* __restrict__ Hf2,
    const u16* __restrict__ W2T, const float* __restrict__ b2,
    const float* __restrict__ W3, const float* __restrict__ b3,
    float* __restrict__ out)
{
    const int b = blockIdx.x, n = blockIdx.y;     // b fastest -> XCD = b
    const int tid = threadIdx.x;
    const int base_bn = b * NTOK + n;
    const int wid = tid >> 6, lane = tid & 63, lrow = lane & 15, quad = lane >> 4;

    __shared__ __align__(16) u16 s1h[DD];        // f16 s1' row, 1 KB
    __shared__ __align__(16) char mbuf[49152];   // Atile 16K + Btile 32K | gh 34K + w3t 8.25K
    u16* Atile = (u16*)mbuf;                     // [128][64] swizzled, f16
    u16* Btile = (u16*)(mbuf + 16384);           // [256][64] swizzled, f16
    u16* gh    = (u16*)mbuf;                     // [128][136] epilogue overlay
    u16* w3t   = (u16*)(mbuf + 34816);           // W3^T padded [16][264], epilogue-only

    // ---- phase 0 ----
    {
        int k = tid;  // 512 threads == DD
        s1h[k] = Hf1b[(size_t)base_bn * DD + k];   // b1 + u[n] already folded
    }
    const int mrow = tid >> 2, seg = tid & 3, swA = mrow & 7;
    // B-DMA lane source pointer: q-invariant swizzle (R0-proven)
    const int csrc = lane >> 3, wsrc = lane & 7;
    const u16* bsrc_lane = W2T + csrc * DD + ((wsrc ^ csrc) << 3);
    __syncthreads();

    const int wm = wid >> 2, wn = wid & 3;       // main GEMM 2x4 wave grid
    floatx4 acc[4][4];
#pragma unroll
    for (int i = 0; i < 4; ++i)
#pragma unroll
        for (int j = 0; j < 4; ++j) acc[i][j] = (floatx4)(0.0f);

    const u16* hf2p = Hf2 + (size_t)(b * NTOK + mrow) * DD;

    const f16x2 zh = {(_Float16)0.0f, (_Float16)0.0f};
    auto hp2 = [&](u32 h, u32 s) -> u32 {
        union { u32 u; f16x2 v; } H, S, O;
        H.u = h; S.u = s;
        O.v = __builtin_elementwise_max(H.v + S.v, zh);
        return O.u;
    };

    // ---- K loop (R8 structure; A-stage = packed add+relu only) ----
    for (int kc = 0; kc < 8; ++kc) {
        const int k0 = kc * 64;
        // stage B via LDS-DMA first (zero data regs; latency hidden by stage-A)
#pragma unroll
        for (int q = 0; q < 4; ++q) {
            const int slot = wid * 4 + q;        // wave-uniform
            __builtin_amdgcn_global_load_lds(
                (const __attribute__((address_space(1))) u32*)(bsrc_lane + slot * 8 * DD + k0),
                (__attribute__((address_space(3))) u32*)(Btile + slot * 512), 16, 0, 0);
        }

        const int kb = k0 + seg * 16;
        {   // stage A: h = relu(hf2' + s1'), 16 f16/thread
            uint4 hv  = *(const uint4*)(hf2p + kb);
            uint4 hw  = *(const uint4*)(hf2p + kb + 8);
            uint4 sv  = *(const uint4*)(s1h + kb);
            uint4 sw2 = *(const uint4*)(s1h + kb + 8);
            uint4 o0 = make_uint4(hp2(hv.x, sv.x), hp2(hv.y, sv.y),
                                  hp2(hv.z, sv.z), hp2(hv.w, sv.w));
            uint4 o1 = make_uint4(hp2(hw.x, sw2.x), hp2(hw.y, sw2.y),
                                  hp2(hw.z, sw2.z), hp2(hw.w, sw2.w));
            *(uint4*)(Atile + mrow * 64 + (((seg * 2    ) ^ swA) << 3)) = o0;
            *(uint4*)(Atile + mrow * 64 + (((seg * 2 + 1) ^ swA) << 3)) = o1;
        }
        __syncthreads();   // vmcnt(0)+lgkmcnt(0) drain: Atile and B-DMA ready
#pragma unroll
        for (int ks = 0; ks < 2; ++ks) {
            const int ch = ks * 4 + quad;
            f16x8 afr[4], bfr[4];
#pragma unroll
            for (int i = 0; i < 4; ++i) {
                int r = wm * 64 + i * 16 + lrow;
                afr[i] = *(const f16x8*)(Atile + r * 64 + ((ch ^ (r & 7)) << 3));
            }
#pragma unroll
            for (int j = 0; j < 4; ++j) {
                int c = wn * 64 + j * 16 + lrow;
                bfr[j] = *(const f16x8*)(Btile + c * 64 + ((ch ^ (c & 7)) << 3));
            }
#pragma unroll
            for (int i = 0; i < 4; ++i)
#pragma unroll
                for (int j = 0; j < 4; ++j)
                    acc[i][j] = __builtin_amdgcn_mfma_f32_16x16x32_f16(afr[i], bfr[j], acc[i][j], 0, 0, 0);
        }
        __syncthreads();
    }

    // ---- w3t fill (Btile region dead after K loop) ----
    {   // w3t: W3 (256x4 fp32) transposed, padded to 16 cols, f16
        int c = tid & 15, kb2 = tid >> 4;          // kb2 0..31
        int k0w = kb2 * 8;
        u32 wv[4];
#pragma unroll
        for (int p = 0; p < 4; ++p) {
            int ka = k0w + p * 2;
            u16 va = (c < 4) ? f2h(W3[ka * 4 + c])       : (u16)0;
            u16 vb = (c < 4) ? f2h(W3[(ka + 1) * 4 + c]) : (u16)0;
            wv[p] = (u32)va | ((u32)vb << 16);
        }
        *(uint2*)(w3t + c * 264 + k0w)     = make_uint2(wv[0], wv[1]);
        *(uint2*)(w3t + c * 264 + k0w + 4) = make_uint2(wv[2], wv[3]);
    }

    // ---- epilogue: relu(acc+b2) -> gh f16 halves -> layer-3 MFMA (R8) ----
    float b2v[4];
#pragma unroll
    for (int j = 0; j < 4; ++j) b2v[j] = b2[wn * 64 + j * 16 + lrow];

    const int smrow = wid * 16;                  // per-wave epilogue row block
    floatx4 acc3 = (floatx4)(0.0f);
#pragma unroll
    for (int half = 0; half < 2; ++half) {
        __syncthreads();
        if ((wn >> 1) == half) {
#pragma unroll
            for (int i = 0; i < 4; ++i)
#pragma unroll
                for (int j = 0; j < 4; ++j)
#pragma unroll
                    for (int r = 0; r < 4; ++r) {
                        int row = wm * 64 + i * 16 + quad * 4 + r;
                        int col = (wn & 1) * 64 + j * 16 + lrow;
                        gh[row * 136 + col] = f2h(fmaxf(acc[i][j][r] + b2v[j], 0.0f));
                    }
        }
        __syncthreads();
#pragma unroll
        for (int ks = 0; ks < 4; ++ks) {
            f16x8 gfrag = *(const f16x8*)(gh + (smrow + lrow) * 136 + ks * 32 + quad * 8);
            f16x8 wfrag = *(const f16x8*)(w3t + lrow * 264 + half * 128 + ks * 32 + quad * 8);
            acc3 = __builtin_amdgcn_mfma_f32_16x16x32_f16(gfrag, wfrag, acc3, 0, 0, 0);
        }
    }
    if (lrow < 4) {
        float bo = b3[lrow];
#pragma unroll
        for (int r = 0; r < 4; ++r) {
            int row = smrow + quad * 4 + r;
            out[(size_t)base_bn * 512 + row * 4 + lrow] = acc3[r] + bo;
        }
    }
}

// ---------------------------------------------------------------------------
extern "C" void kernel_launch(void* const* d_in, const int* in_sizes, int n_in,
                              void* d_out, int out_size, void* d_ws, size_t ws_size,
                              hipStream_t stream)
{
    const float* features  = (const float*)d_in[0];
    const float* positions = (const float*)d_in[1];
    const float* W1 = (const float*)d_in[2];
    const float* b1 = (const float*)d_in[3];
    const float* W2 = (const float*)d_in[4];
    const float* b2 = (const float*)d_in[5];
    const float* W3 = (const float*)d_in[6];
    const float* b3 = (const float*)d_in[7];
    float* out = (float*)d_out;

    char* ws = (char*)d_ws;
    u16* W2T  = (u16*)(ws);                 // 256*512*2 = 262144 B
    u16* Hf1b = (u16*)(ws + 262144);        // 1048576 B
    u16* Hf2  = (u16*)(ws + 1310720);       // 1048576 B (total 2.25 MB)

    prep_k<<<dim3(16, 8, 3), 512, 0, stream>>>(features, W1, W2, b1, positions,
                                               Hf1b, Hf2, W2T);
    fused_main<<<dim3(8, 128), 512, 0, stream>>>(Hf1b, Hf2, W2T, b2, W3, b3, out);
}